// Round 3
// baseline (241.084 us; speedup 1.0000x reference)
//
#include <hip/hip_runtime.h>
#include <hip/hip_bf16.h>
#include <stdint.h>

typedef __attribute__((ext_vector_type(8))) short bf16x8;   // 8 bf16 (4 VGPRs)
typedef __attribute__((ext_vector_type(4))) short s16x4;
typedef __attribute__((ext_vector_type(4))) float f32x4;

#define MFMA16(a, b, c) __builtin_amdgcn_mfma_f32_16x16x32_bf16((a), (b), (c), 0, 0, 0)

__device__ __forceinline__ void gload_lds16(const void* g, void* l) {
  // async global->LDS, 16B/lane; LDS dest = wave-uniform base + lane*16
  __builtin_amdgcn_global_load_lds((const __attribute__((address_space(1))) void*)g,
                                   (__attribute__((address_space(3))) void*)l, 16, 0, 0);
}

// ---- f32 -> bf16 bulk convert (n divisible by 4) ----
__global__ void f32_to_bf16(const float* __restrict__ in, __hip_bfloat16* __restrict__ out, int n) {
  const int i = (blockIdx.x * blockDim.x + threadIdx.x) * 4;
  if (i + 3 < n) {
    const float4 v = *(const float4*)(in + i);
    s16x4 o;
    __hip_bfloat16 h;
    h = __float2bfloat16(v.x); o[0] = *(short*)&h;
    h = __float2bfloat16(v.y); o[1] = *(short*)&h;
    h = __float2bfloat16(v.z); o[2] = *(short*)&h;
    h = __float2bfloat16(v.w); o[3] = *(short*)&h;
    *(s16x4*)((short*)out + i) = o;
  }
}

// C[M,N] = A[M,K] @ W[N,K]^T + bias, optional ReLU. 128x128 tile, BK=32, 4 waves.
// A, W are bf16; bias f32; output bf16 or f32 per F32OUT.
template <int RELU, int F32OUT>
__global__ __launch_bounds__(256, 2) void gemm_bt(
    const __hip_bfloat16* __restrict__ Abf, const __hip_bfloat16* __restrict__ Wbf,
    const float* __restrict__ bias, void* __restrict__ Cv,
    int M, int N, int K) {
  __shared__ __align__(16) __hip_bfloat16 As[128 * 32];
  __shared__ __align__(16) __hip_bfloat16 Bs[128 * 32];
  const int t = threadIdx.x;
  const int w = t >> 6, lane = t & 63;
  const int lr = lane & 15, lg = lane >> 4;
  const int m0 = blockIdx.x * 128, n0 = blockIdx.y * 128;
  const int wr = (w >> 1) * 64, wc = (w & 1) * 64;

  const char* Ag = (const char*)Abf;
  const char* Wg = (const char*)Wbf;
  const size_t ldb = (size_t)K * 2;  // row bytes

  f32x4 acc[4][4] = {};

  // staging geometry: flat byte o=(i*4+w)*1024+lane*16 over the 8KB tile
  const int o0 = (w << 10) + lane * 16;
  const int o1 = o0 + 4096;
  const int r0 = o0 >> 6, c0 = o0 & 63;
  const int r1 = o1 >> 6, c1 = o1 & 63;

  for (int kt = 0; kt < K; kt += 32) {
    if (kt) __syncthreads();
    gload_lds16(Ag + (size_t)(m0 + r0) * ldb + kt * 2 + c0, (char*)As + (w << 10));
    gload_lds16(Ag + (size_t)(m0 + r1) * ldb + kt * 2 + c1, (char*)As + 4096 + (w << 10));
    gload_lds16(Wg + (size_t)(n0 + r0) * ldb + kt * 2 + c0, (char*)Bs + (w << 10));
    gload_lds16(Wg + (size_t)(n0 + r1) * ldb + kt * 2 + c1, (char*)Bs + 4096 + (w << 10));
    __syncthreads();

    bf16x8 af[4], bfv[4];
#pragma unroll
    for (int mi = 0; mi < 4; ++mi)
      af[mi] = *(const bf16x8*)((const char*)As + ((wr + mi * 16 + lr) << 6) + (lg << 4));
#pragma unroll
    for (int ni = 0; ni < 4; ++ni)
      bfv[ni] = *(const bf16x8*)((const char*)Bs + ((wc + ni * 16 + lr) << 6) + (lg << 4));
#pragma unroll
    for (int mi = 0; mi < 4; ++mi)
#pragma unroll
      for (int ni = 0; ni < 4; ++ni)
        acc[mi][ni] = MFMA16(af[mi], bfv[ni], acc[mi][ni]);
  }

#pragma unroll
  for (int ni = 0; ni < 4; ++ni) {
    const int col = n0 + wc + ni * 16 + lr;
    const float bv = bias[col];
#pragma unroll
    for (int mi = 0; mi < 4; ++mi) {
      const int row = m0 + wr + mi * 16 + lg * 4;
#pragma unroll
      for (int j = 0; j < 4; ++j) {
        float v = acc[mi][ni][j] + bv;
        if (RELU) v = fmaxf(v, 0.0f);
        const size_t idx = (size_t)(row + j) * N + col;
        if (F32OUT)
          ((float*)Cv)[idx] = v;
        else
          ((__hip_bfloat16*)Cv)[idx] = __float2bfloat16(v);
      }
    }
  }
}

// Fused cross-attention — correctness-first: no swizzles, no global_load_lds.
// Block = (64 q-rows, head h, batch b); 4 waves x 16 q-rows.
// LDS: Vt (linear, 32KB) | Ks (linear, 32KB; reused for P tiles) = 64KB.
__global__ __launch_bounds__(256, 2) void attn_fused(
    const __hip_bfloat16* __restrict__ Qb, const __hip_bfloat16* __restrict__ Kb,
    const __hip_bfloat16* __restrict__ Vb, const float* __restrict__ padm,
    const float* __restrict__ seqm, __hip_bfloat16* __restrict__ O) {
  constexpr int S = 256, E = 1024, Nq = 4096;
  constexpr float NEGV = -1e9f;
  __shared__ __align__(16) char smem[65536];
  char* VtB = smem;           // V^T [64 d][256 s] shorts, 512B rows, LINEAR
  char* KsB = smem + 32768;   // K   [256 s][64 d] shorts, 128B rows, LINEAR; later P

  const int t = threadIdx.x;
  const int w = t >> 6, lane = t & 63;
  const int lr = lane & 15, lg = lane >> 4;
  const int q0 = blockIdx.x * 64, h = blockIdx.y, b = blockIdx.z;

  // --- stage K (register path, linear): 256 threads x 8 x 16B ---
  const char* Kg = (const char*)(Kb + (size_t)b * S * E + h * 64);
#pragma unroll
  for (int i = 0; i < 8; ++i) {
    const int o = (i << 12) + t * 16;          // 0..32767
    const int s = o >> 7, c = o & 127;
    *(bf16x8*)(KsB + o) = *(const bf16x8*)(Kg + (size_t)s * (E * 2) + c);
  }
  // --- stage V transposed (linear): thread t owns source row s=t ---
  {
    const short* Vg = (const short*)Vb + ((size_t)b * S + t) * E + h * 64;
    short* Vt = (short*)VtB;
#pragma unroll
    for (int d0 = 0; d0 < 64; d0 += 8) {
      bf16x8 v = *(const bf16x8*)(Vg + d0);
#pragma unroll
      for (int j = 0; j < 8; ++j) {
        const int d = d0 + j;
        Vt[(d << 8) + t] = v[j];
      }
    }
  }
  __syncthreads();

  // --- Q fragments (direct from global) ---
  const int qw = q0 + w * 16;
  const short* Qg = (const short*)Qb + (size_t)(b * Nq + qw + lr) * E + h * 64;
  const bf16x8 aq0 = *(const bf16x8*)(Qg + (lg << 3));
  const bf16x8 aq1 = *(const bf16x8*)(Qg + 32 + (lg << 3));

  // --- scores: S[16q x 256s], D-layout row=(lg*4+j)=q, col=lr(+16*ni)=s ---
  f32x4 sc[16];
#pragma unroll
  for (int ni = 0; ni < 16; ++ni) {
    const int s = ni * 16 + lr;
    f32x4 a = {0.f, 0.f, 0.f, 0.f};
    const bf16x8 bk0 = *(const bf16x8*)(KsB + (s << 7) + (lg << 4));
    const bf16x8 bk1 = *(const bf16x8*)(KsB + (s << 7) + 64 + (lg << 4));
    a = MFMA16(aq0, bk0, a);
    a = MFMA16(aq1, bk1, a);
    sc[ni] = a;
  }

  // --- mask + scale + softmax (rows live across 16 lanes of same lg-group) ---
  float pad4[4];
#pragma unroll
  for (int j = 0; j < 4; ++j)
    pad4[j] = padm[(size_t)b * Nq + qw + lg * 4 + j];

  float mrow[4] = {NEGV, NEGV, NEGV, NEGV};
#pragma unroll
  for (int ni = 0; ni < 16; ++ni) {
    const float ms = seqm[b * S + ni * 16 + lr];
#pragma unroll
    for (int j = 0; j < 4; ++j) {
      float v = (ms != 0.f && pad4[j] != 0.f) ? sc[ni][j] * 0.125f : NEGV;
      sc[ni][j] = v;
      mrow[j] = fmaxf(mrow[j], v);
    }
  }
#pragma unroll
  for (int j = 0; j < 4; ++j) {
#pragma unroll
    for (int d = 1; d < 16; d <<= 1) mrow[j] = fmaxf(mrow[j], __shfl_xor(mrow[j], d));
  }
  float ssum[4] = {0.f, 0.f, 0.f, 0.f};
#pragma unroll
  for (int ni = 0; ni < 16; ++ni)
#pragma unroll
    for (int j = 0; j < 4; ++j) {
      const float e = __expf(sc[ni][j] - mrow[j]);
      sc[ni][j] = e;
      ssum[j] += e;
    }
#pragma unroll
  for (int j = 0; j < 4; ++j) {
#pragma unroll
    for (int d = 1; d < 16; d <<= 1) ssum[j] += __shfl_xor(ssum[j], d);
  }

  __syncthreads();  // all Ks reads done before P overwrites the region

  // --- write P (unnormalized exp) to LINEAR per-wave tile in Ks region ---
  char* PwB = KsB + (w << 13);  // 8KB per wave: [16 q][256 s] shorts, 512B rows
#pragma unroll
  for (int ni = 0; ni < 16; ++ni)
#pragma unroll
    for (int j = 0; j < 4; ++j) {
      const int r = lg * 4 + j;
      *(__hip_bfloat16*)(PwB + (r << 9) + ((ni * 16 + lr) << 1)) =
          __float2bfloat16(sc[ni][j]);
    }
  __syncthreads();  // cross-lane LDS visibility before PV reads

  // --- PV: O[16q x 64d] = P @ V ---
  bf16x8 pa[8];
#pragma unroll
  for (int ks = 0; ks < 8; ++ks)
    pa[ks] = *(const bf16x8*)(PwB + (lr << 9) + (ks << 6) + (lg << 4));

  float inv[4];
#pragma unroll
  for (int j = 0; j < 4; ++j) inv[j] = 1.0f / ssum[j];

  __hip_bfloat16* Og = O + (size_t)(b * Nq + qw) * E + h * 64;
#pragma unroll
  for (int nd = 0; nd < 4; ++nd) {
    f32x4 a = {0.f, 0.f, 0.f, 0.f};
    const int d = nd * 16 + lr;
#pragma unroll
    for (int ks = 0; ks < 8; ++ks) {
      const bf16x8 bv = *(const bf16x8*)(VtB + (d << 9) + (ks << 6) + (lg << 4));
      a = MFMA16(pa[ks], bv, a);
    }
#pragma unroll
    for (int j = 0; j < 4; ++j)
      Og[(size_t)(lg * 4 + j) * E + nd * 16 + lr] = __float2bfloat16(a[j] * inv[j]);
  }
}

extern "C" void kernel_launch(void* const* d_in, const int* in_sizes, int n_in,
                              void* d_out, int out_size, void* d_ws, size_t ws_size,
                              hipStream_t stream) {
  // All reference tensors are float32.
  const float* x    = (const float*)d_in[0];
  const float* ctx  = (const float*)d_in[1];
  const float* padm = (const float*)d_in[2];
  const float* seqm = (const float*)d_in[3];
  const float* Wq_w = (const float*)d_in[4];
  const float* Wq_b = (const float*)d_in[5];
  const float* Wk_w = (const float*)d_in[6];
  const float* Wk_b = (const float*)d_in[7];
  const float* Wv_w = (const float*)d_in[8];
  const float* Wv_b = (const float*)d_in[9];
  const float* P1_w = (const float*)d_in[10];
  const float* P1_b = (const float*)d_in[11];
  const float* P2_w = (const float*)d_in[12];
  const float* P2_b = (const float*)d_in[13];
  float* out = (float*)d_out;

  char* ws = (char*)d_ws;
  size_t off = 0;
  auto alloc = [&](size_t bytes) { char* p = ws + off; off += (bytes + 255) & ~(size_t)255; return p; };
  __hip_bfloat16* Q    = (__hip_bfloat16*)alloc(16384ull * 1024 * 2);  // 32MB (later O1)
  __hip_bfloat16* AO   = (__hip_bfloat16*)alloc(16384ull * 1024 * 2);  // 32MB
  __hip_bfloat16* xb   = (__hip_bfloat16*)alloc(16384ull * 512 * 2);   // 16MB
  __hip_bfloat16* ctxb = (__hip_bfloat16*)alloc(1024ull * 768 * 2);
  __hip_bfloat16* Kp   = (__hip_bfloat16*)alloc(1024ull * 1024 * 2);
  __hip_bfloat16* Vp   = (__hip_bfloat16*)alloc(1024ull * 1024 * 2);
  __hip_bfloat16* Wqb  = (__hip_bfloat16*)alloc(1024ull * 512 * 2);
  __hip_bfloat16* Wkb  = (__hip_bfloat16*)alloc(1024ull * 768 * 2);
  __hip_bfloat16* Wvb  = (__hip_bfloat16*)alloc(1024ull * 768 * 2);
  __hip_bfloat16* P1b  = (__hip_bfloat16*)alloc(1024ull * 1024 * 2);
  __hip_bfloat16* P2b  = (__hip_bfloat16*)alloc(512ull * 1024 * 2);
  __hip_bfloat16* O1   = Q;  // reuse Q after attention

  const dim3 blk(256, 1, 1);
  auto cvt = [&](const float* src, __hip_bfloat16* dst, int n) {
    f32_to_bf16<<<dim3((n + 1023) / 1024, 1, 1), blk, 0, stream>>>(src, dst, n);
  };
  cvt(x,    xb,   16384 * 512);
  cvt(ctx,  ctxb, 1024 * 768);
  cvt(Wq_w, Wqb,  1024 * 512);
  cvt(Wk_w, Wkb,  1024 * 768);
  cvt(Wv_w, Wvb,  1024 * 768);
  cvt(P1_w, P1b,  1024 * 1024);
  cvt(P2_w, P2b,  512 * 1024);

  gemm_bt<0, 0><<<dim3(128, 8, 1), blk, 0, stream>>>(xb,   Wqb, Wq_b, Q,   16384, 1024, 512);
  gemm_bt<0, 0><<<dim3(8, 8, 1),   blk, 0, stream>>>(ctxb, Wkb, Wk_b, Kp,  1024, 1024, 768);
  gemm_bt<0, 0><<<dim3(8, 8, 1),   blk, 0, stream>>>(ctxb, Wvb, Wv_b, Vp,  1024, 1024, 768);
  attn_fused<<<dim3(64, 16, 4), blk, 0, stream>>>(Q, Kp, Vp, padm, seqm, AO);
  gemm_bt<1, 0><<<dim3(128, 8, 1), blk, 0, stream>>>(AO, P1b, P1_b, O1,  16384, 1024, 1024);
  gemm_bt<0, 1><<<dim3(128, 4, 1), blk, 0, stream>>>(O1, P2b, P2_b, out, 16384, 512, 1024);
}

// Round 4
// 232.021 us; speedup vs baseline: 1.0391x; 1.0391x over previous
//
#include <hip/hip_runtime.h>
#include <hip/hip_bf16.h>
#include <stdint.h>

typedef __attribute__((ext_vector_type(8))) short bf16x8;   // 8 bf16 (4 VGPRs)
typedef __attribute__((ext_vector_type(4))) short s16x4;
typedef __attribute__((ext_vector_type(4))) float f32x4;

#define MFMA16(a, b, c) __builtin_amdgcn_mfma_f32_16x16x32_bf16((a), (b), (c), 0, 0, 0)

__device__ __forceinline__ void gload_lds16(const void* g, void* l) {
  // async global->LDS, 16B/lane; LDS dest = wave-uniform base + lane*16
  __builtin_amdgcn_global_load_lds((const __attribute__((address_space(1))) void*)g,
                                   (__attribute__((address_space(3))) void*)l, 16, 0, 0);
}

// ---- f32 -> bf16 bulk convert (n divisible by 4) ----
__global__ void f32_to_bf16(const float* __restrict__ in, __hip_bfloat16* __restrict__ out, int n) {
  const int i = (blockIdx.x * blockDim.x + threadIdx.x) * 4;
  if (i + 3 < n) {
    const float4 v = *(const float4*)(in + i);
    s16x4 o;
    __hip_bfloat16 h;
    h = __float2bfloat16(v.x); o[0] = *(short*)&h;
    h = __float2bfloat16(v.y); o[1] = *(short*)&h;
    h = __float2bfloat16(v.z); o[2] = *(short*)&h;
    h = __float2bfloat16(v.w); o[3] = *(short*)&h;
    *(s16x4*)((short*)out + i) = o;
  }
}

// C[M,N] = A[M,K] @ W[N,K]^T + bias, optional ReLU. 128x128 tile, BK=32, 4 waves.
template <int RELU, int F32OUT>
__global__ __launch_bounds__(256, 2) void gemm_bt(
    const __hip_bfloat16* __restrict__ Abf, const __hip_bfloat16* __restrict__ Wbf,
    const float* __restrict__ bias, void* __restrict__ Cv,
    int M, int N, int K) {
  __shared__ __align__(16) __hip_bfloat16 As[128 * 32];
  __shared__ __align__(16) __hip_bfloat16 Bs[128 * 32];
  const int t = threadIdx.x;
  const int w = t >> 6, lane = t & 63;
  const int lr = lane & 15, lg = lane >> 4;
  const int m0 = blockIdx.x * 128, n0 = blockIdx.y * 128;
  const int wr = (w >> 1) * 64, wc = (w & 1) * 64;

  const char* Ag = (const char*)Abf;
  const char* Wg = (const char*)Wbf;
  const size_t ldb = (size_t)K * 2;  // row bytes

  f32x4 acc[4][4] = {};

  const int o0 = (w << 10) + lane * 16;
  const int o1 = o0 + 4096;
  const int r0 = o0 >> 6, c0 = o0 & 63;
  const int r1 = o1 >> 6, c1 = o1 & 63;

  for (int kt = 0; kt < K; kt += 32) {
    if (kt) __syncthreads();
    gload_lds16(Ag + (size_t)(m0 + r0) * ldb + kt * 2 + c0, (char*)As + (w << 10));
    gload_lds16(Ag + (size_t)(m0 + r1) * ldb + kt * 2 + c1, (char*)As + 4096 + (w << 10));
    gload_lds16(Wg + (size_t)(n0 + r0) * ldb + kt * 2 + c0, (char*)Bs + (w << 10));
    gload_lds16(Wg + (size_t)(n0 + r1) * ldb + kt * 2 + c1, (char*)Bs + 4096 + (w << 10));
    __syncthreads();

    bf16x8 af[4], bfv[4];
#pragma unroll
    for (int mi = 0; mi < 4; ++mi)
      af[mi] = *(const bf16x8*)((const char*)As + ((wr + mi * 16 + lr) << 6) + (lg << 4));
#pragma unroll
    for (int ni = 0; ni < 4; ++ni)
      bfv[ni] = *(const bf16x8*)((const char*)Bs + ((wc + ni * 16 + lr) << 6) + (lg << 4));
#pragma unroll
    for (int mi = 0; mi < 4; ++mi)
#pragma unroll
      for (int ni = 0; ni < 4; ++ni)
        acc[mi][ni] = MFMA16(af[mi], bfv[ni], acc[mi][ni]);
  }

#pragma unroll
  for (int ni = 0; ni < 4; ++ni) {
    const int col = n0 + wc + ni * 16 + lr;
    const float bv = bias[col];
#pragma unroll
    for (int mi = 0; mi < 4; ++mi) {
      const int row = m0 + wr + mi * 16 + lg * 4;
#pragma unroll
      for (int j = 0; j < 4; ++j) {
        float v = acc[mi][ni][j] + bv;
        if (RELU) v = fmaxf(v, 0.0f);
        const size_t idx = (size_t)(row + j) * N + col;
        if (F32OUT)
          ((float*)Cv)[idx] = v;
        else
          ((__hip_bfloat16*)Cv)[idx] = __float2bfloat16(v);
      }
    }
  }
}

// Fused cross-attention, XOR-swizzled LDS (G4 / m214 recipe).
// Block = (64 q-rows, head h, batch b); 4 waves x 16 q-rows.
// LDS: Vt (swizzled, 32KB) | Ks (swizzled, 32KB; reused for P tiles) = 64KB.
// All swizzles: byte-in-row ^= ((row&7)<<4), store and read identically.
__global__ __launch_bounds__(256, 2) void attn_fused(
    const __hip_bfloat16* __restrict__ Qb, const __hip_bfloat16* __restrict__ Kb,
    const __hip_bfloat16* __restrict__ Vb, const float* __restrict__ padm,
    const float* __restrict__ seqm, __hip_bfloat16* __restrict__ O) {
  constexpr int S = 256, E = 1024, Nq = 4096;
  constexpr float NEGV = -1e9f;
  __shared__ __align__(16) char smem[65536];
  char* VtB = smem;           // V^T [64 d][256 s] shorts, 512B rows, byte ^= (d&7)<<4
  char* KsB = smem + 32768;   // K   [256 s][64 d] shorts, 128B rows, byte ^= (s&7)<<4

  const int t = threadIdx.x;
  const int w = t >> 6, lane = t & 63;
  const int lr = lane & 15, lg = lane >> 4;
  const int q0 = blockIdx.x * 64, h = blockIdx.y, b = blockIdx.z;

  // --- stage K via global_load_lds: linear LDS dest + inverse-swizzled SOURCE ---
  const char* Kg = (const char*)(Kb + (size_t)b * S * E + h * 64);
#pragma unroll
  for (int i = 0; i < 8; ++i) {
    const int o = ((i * 4 + w) << 10) + lane * 16;  // linear byte in 32KB tile
    const int s = o >> 7, bc = o & 127;
    const int gc = bc ^ ((s & 7) << 4);             // pre-swizzle the global column
    gload_lds16(Kg + (size_t)s * (E * 2) + gc, KsB + ((i * 4 + w) << 10));
  }
  // --- stage V transposed+swizzled: thread t owns source row s=t ---
  {
    const short* Vg = (const short*)Vb + ((size_t)b * S + t) * E + h * 64;
    short* Vt = (short*)VtB;
#pragma unroll
    for (int d0 = 0; d0 < 64; d0 += 8) {
      bf16x8 v = *(const bf16x8*)(Vg + d0);
#pragma unroll
      for (int j = 0; j < 8; ++j) {
        const int d = d0 + j;
        Vt[(d << 8) + (t ^ ((d & 7) << 3))] = v[j];  // byte: (t<<1)^((d&7)<<4)
      }
    }
  }
  __syncthreads();

  // --- Q fragments (direct from global) ---
  const int qw = q0 + w * 16;
  const short* Qg = (const short*)Qb + (size_t)(b * Nq + qw + lr) * E + h * 64;
  const bf16x8 aq0 = *(const bf16x8*)(Qg + (lg << 3));
  const bf16x8 aq1 = *(const bf16x8*)(Qg + 32 + (lg << 3));

  // --- scores: S[16q x 256s], D-layout row=(lg*4+j)=q, col=lr(+16*ni)=s ---
  f32x4 sc[16];
  const int swz = (lr & 7) << 4;  // row&7 == lr&7 for s=ni*16+lr, d=nd*16+lr, r=lr
#pragma unroll
  for (int ni = 0; ni < 16; ++ni) {
    const int s = ni * 16 + lr;
    f32x4 a = {0.f, 0.f, 0.f, 0.f};
    const bf16x8 bk0 = *(const bf16x8*)(KsB + (s << 7) + ((lg << 4) ^ swz));
    const bf16x8 bk1 = *(const bf16x8*)(KsB + (s << 7) + ((64 + (lg << 4)) ^ swz));
    a = MFMA16(aq0, bk0, a);
    a = MFMA16(aq1, bk1, a);
    sc[ni] = a;
  }

  // --- mask + scale + softmax (rows live across 16 lanes of same lg-group) ---
  float pad4[4];
#pragma unroll
  for (int j = 0; j < 4; ++j)
    pad4[j] = padm[(size_t)b * Nq + qw + lg * 4 + j];

  float mrow[4] = {NEGV, NEGV, NEGV, NEGV};
#pragma unroll
  for (int ni = 0; ni < 16; ++ni) {
    const float ms = seqm[b * S + ni * 16 + lr];
#pragma unroll
    for (int j = 0; j < 4; ++j) {
      float v = (ms != 0.f && pad4[j] != 0.f) ? sc[ni][j] * 0.125f : NEGV;
      sc[ni][j] = v;
      mrow[j] = fmaxf(mrow[j], v);
    }
  }
#pragma unroll
  for (int j = 0; j < 4; ++j) {
#pragma unroll
    for (int d = 1; d < 16; d <<= 1) mrow[j] = fmaxf(mrow[j], __shfl_xor(mrow[j], d));
  }
  float ssum[4] = {0.f, 0.f, 0.f, 0.f};
#pragma unroll
  for (int ni = 0; ni < 16; ++ni)
#pragma unroll
    for (int j = 0; j < 4; ++j) {
      const float e = __expf(sc[ni][j] - mrow[j]);
      sc[ni][j] = e;
      ssum[j] += e;
    }
#pragma unroll
  for (int j = 0; j < 4; ++j) {
#pragma unroll
    for (int d = 1; d < 16; d <<= 1) ssum[j] += __shfl_xor(ssum[j], d);
  }

  __syncthreads();  // all Ks reads done before P overwrites the region

  // --- write P (unnormalized exp) to swizzled per-wave tile in Ks region ---
  char* PwB = KsB + (w << 13);  // 8KB per wave: [16 q][256 s] shorts, 512B rows
#pragma unroll
  for (int ni = 0; ni < 16; ++ni)
#pragma unroll
    for (int j = 0; j < 4; ++j) {
      const int r = lg * 4 + j;
      *(__hip_bfloat16*)(PwB + (r << 9) + (((ni * 16 + lr) << 1) ^ ((r & 7) << 4))) =
          __float2bfloat16(sc[ni][j]);
    }
  __syncthreads();  // cross-lane LDS visibility before PV reads

  // --- PV: O[16q x 64d] = P @ V ---
  bf16x8 pa[8];
#pragma unroll
  for (int ks = 0; ks < 8; ++ks)
    pa[ks] = *(const bf16x8*)(PwB + (lr << 9) + (((ks << 6) + (lg << 4)) ^ swz));

  float inv[4];
#pragma unroll
  for (int j = 0; j < 4; ++j) inv[j] = 1.0f / ssum[j];

  __hip_bfloat16* Og = O + (size_t)(b * Nq + qw) * E + h * 64;
#pragma unroll
  for (int nd = 0; nd < 4; ++nd) {
    f32x4 a = {0.f, 0.f, 0.f, 0.f};
    const int d = nd * 16 + lr;  // d&7 == lr&7
#pragma unroll
    for (int ks = 0; ks < 8; ++ks) {
      const bf16x8 bv = *(const bf16x8*)(VtB + (d << 9) + (((ks << 6) + (lg << 4)) ^ swz));
      a = MFMA16(pa[ks], bv, a);
    }
#pragma unroll
    for (int j = 0; j < 4; ++j)
      Og[(size_t)(lg * 4 + j) * E + nd * 16 + lr] = __float2bfloat16(a[j] * inv[j]);
  }
}

extern "C" void kernel_launch(void* const* d_in, const int* in_sizes, int n_in,
                              void* d_out, int out_size, void* d_ws, size_t ws_size,
                              hipStream_t stream) {
  // All reference tensors are float32.
  const float* x    = (const float*)d_in[0];
  const float* ctx  = (const float*)d_in[1];
  const float* padm = (const float*)d_in[2];
  const float* seqm = (const float*)d_in[3];
  const float* Wq_w = (const float*)d_in[4];
  const float* Wq_b = (const float*)d_in[5];
  const float* Wk_w = (const float*)d_in[6];
  const float* Wk_b = (const float*)d_in[7];
  const float* Wv_w = (const float*)d_in[8];
  const float* Wv_b = (const float*)d_in[9];
  const float* P1_w = (const float*)d_in[10];
  const float* P1_b = (const float*)d_in[11];
  const float* P2_w = (const float*)d_in[12];
  const float* P2_b = (const float*)d_in[13];
  float* out = (float*)d_out;

  char* ws = (char*)d_ws;
  size_t off = 0;
  auto alloc = [&](size_t bytes) { char* p = ws + off; off += (bytes + 255) & ~(size_t)255; return p; };
  __hip_bfloat16* Q    = (__hip_bfloat16*)alloc(16384ull * 1024 * 2);  // 32MB (later O1)
  __hip_bfloat16* AO   = (__hip_bfloat16*)alloc(16384ull * 1024 * 2);  // 32MB
  __hip_bfloat16* xb   = (__hip_bfloat16*)alloc(16384ull * 512 * 2);   // 16MB
  __hip_bfloat16* ctxb = (__hip_bfloat16*)alloc(1024ull * 768 * 2);
  __hip_bfloat16* Kp   = (__hip_bfloat16*)alloc(1024ull * 1024 * 2);
  __hip_bfloat16* Vp   = (__hip_bfloat16*)alloc(1024ull * 1024 * 2);
  __hip_bfloat16* Wqb  = (__hip_bfloat16*)alloc(1024ull * 512 * 2);
  __hip_bfloat16* Wkb  = (__hip_bfloat16*)alloc(1024ull * 768 * 2);
  __hip_bfloat16* Wvb  = (__hip_bfloat16*)alloc(1024ull * 768 * 2);
  __hip_bfloat16* P1b  = (__hip_bfloat16*)alloc(1024ull * 1024 * 2);
  __hip_bfloat16* P2b  = (__hip_bfloat16*)alloc(512ull * 1024 * 2);
  __hip_bfloat16* O1   = Q;  // reuse Q after attention

  const dim3 blk(256, 1, 1);
  auto cvt = [&](const float* src, __hip_bfloat16* dst, int n) {
    f32_to_bf16<<<dim3((n + 1023) / 1024, 1, 1), blk, 0, stream>>>(src, dst, n);
  };
  cvt(x,    xb,   16384 * 512);
  cvt(ctx,  ctxb, 1024 * 768);
  cvt(Wq_w, Wqb,  1024 * 512);
  cvt(Wk_w, Wkb,  1024 * 768);
  cvt(Wv_w, Wvb,  1024 * 768);
  cvt(P1_w, P1b,  1024 * 1024);
  cvt(P2_w, P2b,  512 * 1024);

  gemm_bt<0, 0><<<dim3(128, 8, 1), blk, 0, stream>>>(xb,   Wqb, Wq_b, Q,   16384, 1024, 512);
  gemm_bt<0, 0><<<dim3(8, 8, 1),   blk, 0, stream>>>(ctxb, Wkb, Wk_b, Kp,  1024, 1024, 768);
  gemm_bt<0, 0><<<dim3(8, 8, 1),   blk, 0, stream>>>(ctxb, Wvb, Wv_b, Vp,  1024, 1024, 768);
  attn_fused<<<dim3(64, 16, 4), blk, 0, stream>>>(Q, Kp, Vp, padm, seqm, AO);
  gemm_bt<1, 0><<<dim3(128, 8, 1), blk, 0, stream>>>(AO, P1b, P1_b, O1,  16384, 1024, 1024);
  gemm_bt<0, 1><<<dim3(128, 4, 1), blk, 0, stream>>>(O1, P2b, P2_b, out, 16384, 512, 1024);
}